// Round 12
// baseline (512.956 us; speedup 1.0000x reference)
//
#include <hip/hip_runtime.h>
#include <cstdint>
#include <cstddef>

typedef unsigned int uint32;
typedef unsigned short ushort16;   // scalar ushort (bf16 storage)
typedef __attribute__((ext_vector_type(8))) short short8;
typedef __attribute__((ext_vector_type(4))) float floatx4;

__device__ __forceinline__ ushort16 f2bf(float f) {
    uint32 u = __builtin_bit_cast(uint32, f);
    uint32 r = (u + 0x7fffu + ((u >> 16) & 1u)) >> 16;   // RNE
    return (ushort16)r;
}
__device__ __forceinline__ float bf2f(ushort16 h) {
    uint32 u = ((uint32)h) << 16;
    return __builtin_bit_cast(float, u);
}

#define PBS 4096

// ---------------- graph prep: bucketed CSR build ----------------
// bucket_hist is fused into prep_fused_kernel (launch-count cut, R17).
__global__ __launch_bounds__(256) void bucket_scan_kernel(
    const int* __restrict__ bcnt, int* __restrict__ bucketOff,
    int* __restrict__ cursorA, int NBUCK, int E) {
    __shared__ int a[512], b[512];
    int t = threadIdx.x;
    a[t] = (t < NBUCK) ? bcnt[t] : 0;
    a[t + 256] = (t + 256 < NBUCK) ? bcnt[t + 256] : 0;
    __syncthreads();
    int* cur = a; int* nxt = b;
    for (int o = 1; o < 512; o <<= 1) {
#pragma unroll
        for (int i = t; i < 512; i += 256)
            nxt[i] = cur[i] + ((i >= o) ? cur[i - o] : 0);
        __syncthreads();
        int* tmp = cur; cur = nxt; nxt = tmp;
    }
#pragma unroll
    for (int i = t; i < 512; i += 256) {
        if (i < NBUCK) {
            int off = (i == 0) ? 0 : cur[i - 1];
            bucketOff[i] = off;
            cursorA[i] = off;
        }
    }
    if (t == 0) bucketOff[NBUCK] = E;
}

__global__ __launch_bounds__(256) void bucket_partition_kernel(
    const int* __restrict__ src, const int* __restrict__ dst,
    int* __restrict__ cursorA, uint32* __restrict__ ebuf, int E, int NBUCK) {
    __shared__ int lbase[512];
    int tid = threadIdx.x;
    for (int b = tid; b < NBUCK; b += 256) lbase[b] = 0;
    __syncthreads();
    int e0 = blockIdx.x * PBS;
    int e1 = e0 + PBS; if (e1 > E) e1 = E;
    for (int j = e0 + tid; j < e1; j += 256)
        atomicAdd(&lbase[dst[j] >> 8], 1);
    __syncthreads();
    for (int b = tid; b < NBUCK; b += 256) {
        int c = lbase[b];
        lbase[b] = c ? atomicAdd(&cursorA[b], c) : 0;
    }
    __syncthreads();
    for (int j = e0 + tid; j < e1; j += 256) {
        int d = dst[j];
        int p = atomicAdd(&lbase[d >> 8], 1);
        ebuf[p] = ((uint32)src[j] << 8) | (uint32)(d & 255);
    }
}

__global__ __launch_bounds__(256) void bucket_build_kernel(
    const uint32* __restrict__ ebuf, const int* __restrict__ bucketOff,
    int* __restrict__ row_ptr, float* __restrict__ degf,
    int* __restrict__ csr, int N, int E) {
    __shared__ int ldeg[256];
    __shared__ int lscan[256];
    __shared__ int lcur[256];
    int b = blockIdx.x, t = threadIdx.x;
    int n0 = b << 8;
    int s = bucketOff[b], e = bucketOff[b + 1];
    ldeg[t] = 0;
    __syncthreads();
    for (int j = s + t; j < e; j += 256)
        atomicAdd(&ldeg[ebuf[j] & 255u], 1);
    __syncthreads();
    int v = ldeg[t];
    lscan[t] = v;
    __syncthreads();
    for (int off = 1; off < 256; off <<= 1) {
        int x = (t >= off) ? lscan[t - off] : 0;
        __syncthreads();
        lscan[t] += x;
        __syncthreads();
    }
    int excl = lscan[t] - v;
    int node = n0 + t;
    if (node < N) {
        row_ptr[node] = s + excl;
        degf[node] = (float)(v > 0 ? v : 1);
    }
    lcur[t] = s + excl;
    __syncthreads();
    for (int j = s + t; j < e; j += 256) {
        uint32 en = ebuf[j];
        int p = atomicAdd(&lcur[en & 255u], 1);
        csr[p] = (int)(en >> 8);
    }
    if (b == 0 && t == 0) row_ptr[N] = E;
}

// ---------------- fused prep: bucket hist + bf16 conv + weight prep ----------
// Block ranges:
//   [0, HB)                : dst bucket histogram (needs bcnt pre-zeroed)
//   [HB, HB+CB)            : in_feat fp32 -> bf16 pack
//   [HB+CB, HB+CB+384)     : weight transpose/pad, bf16 hi+lo
__global__ __launch_bounds__(256) void prep_fused_kernel(
    const int* __restrict__ dst, int* __restrict__ bcnt, int E, int NBUCK, int HB,
    const float* __restrict__ x, ushort16* __restrict__ y, int n8, int CB,
    const float* __restrict__ W0s, const float* __restrict__ W0n,
    const float* __restrict__ W1s, const float* __restrict__ W1n,
    const float* __restrict__ W2s, const float* __restrict__ W2n,
    ushort16* __restrict__ Whi, ushort16* __restrict__ Wlo) {
    __shared__ int l[512];
    int t = threadIdx.x;
    int bid = blockIdx.x;
    if (bid < HB) {
        for (int b = t; b < NBUCK; b += 256) l[b] = 0;
        __syncthreads();
        int e0 = bid * PBS;
        int e1 = e0 + PBS; if (e1 > E) e1 = E;
        for (int j = e0 + t; j < e1; j += 256)
            atomicAdd(&l[dst[j] >> 8], 1);
        __syncthreads();
        for (int b = t; b < NBUCK; b += 256) {
            int c = l[b];
            if (c) atomicAdd(&bcnt[b], c);
        }
        return;
    }
    bid -= HB;
    if (bid < CB) {
        int i = bid * 256 + t;
        if (i >= n8) return;
        const float4 a = *(const float4*)(x + (size_t)i * 8);
        const float4 b = *(const float4*)(x + (size_t)i * 8 + 4);
        uint4 o;
        o.x = (uint32)f2bf(a.x) | ((uint32)f2bf(a.y) << 16);
        o.y = (uint32)f2bf(a.z) | ((uint32)f2bf(a.w) << 16);
        o.z = (uint32)f2bf(b.x) | ((uint32)f2bf(b.y) << 16);
        o.w = (uint32)f2bf(b.z) | ((uint32)f2bf(b.w) << 16);
        *(uint4*)(y + (size_t)i * 8) = o;
        return;
    }
    bid -= CB;
    {
        int mat = bid >> 6;
        int idx = (bid & 63) * 256 + t;
        const float* Wt[6] = {W0s, W0n, W1s, W1n, W2s, W2n};
        const int Kt[6] = {128, 128, 128, 128, 118, 118};
        const int Mt[6] = {128, 128, 118, 118, 103, 103};
        int n = idx >> 7, k = idx & 127;
        int K = Kt[mat], M = Mt[mat];
        float w = (k < K && n < M) ? Wt[mat][(size_t)k * M + n] : 0.f;
        ushort16 h = f2bf(w);
        float lo = w - bf2f(h);
        Whi[(size_t)mat * 16384 + idx] = h;
        Wlo[(size_t)mat * 16384 + idx] = f2bf(lo);
    }
}

// ---------------- bf16 CSR pre-aggregation (layers 1-3), 8-lane rows ------
// R20: counters said 23 VALU insts/edge but unpack+add is only ~4 — the rest
// is per-edge 64-bit gather address math DUPLICATED across all lanes of a
// row group. New geometry: 8 lanes/row x 32B/lane (two coalesced 128B
// half-row loads), 8 edge slots (matches deg~16 -> ~2 main iters; remainder
// keeps 2 loads in flight). Halves per-edge address VALU. Same adds per dim
// (grouping differs; R11 showed absmax robust to reassociation).
template<int DUMMY>
__global__ __launch_bounds__(256) void aggregate_pre_kernel(
    const ushort16* __restrict__ h,
    const int* __restrict__ row_ptr, const int* __restrict__ csr,
    const float* __restrict__ degf, ushort16* __restrict__ aggH, int N) {
    int wid = threadIdx.x >> 6;
    int lane = threadIdx.x & 63;
    int node = blockIdx.x * 4 + wid;
    if (node >= N) return;
    int s = row_ptr[node], e = row_ptr[node + 1];
    int c = lane & 7;          // 16B sub-segment within each 128B half-row
    int eo = lane >> 3;        // edge slot 0..7
    float aLo[8] = {}, aHi[8] = {};
    const ushort16* hc = h + (c << 3);   // + c*8 ushorts (16B)
    int j = s + eo;
    // main: 2 edges in flight per lane (4 x uint4 loads)
    for (; j + 8 < e; j += 16) {
        int s0 = csr[j];
        int s1 = csr[j + 8];
        const ushort16* r0 = hc + ((size_t)s0 << 7);
        const ushort16* r1 = hc + ((size_t)s1 << 7);
        uint4 v0a = *(const uint4*)(r0);        // bytes [c*16, +16) of row
        uint4 v0b = *(const uint4*)(r0 + 64);   // bytes [128 + c*16, +16)
        uint4 v1a = *(const uint4*)(r1);
        uint4 v1b = *(const uint4*)(r1 + 64);
        uint32 w0[8] = {v0a.x, v0a.y, v0a.z, v0a.w, v0b.x, v0b.y, v0b.z, v0b.w};
        uint32 w1[8] = {v1a.x, v1a.y, v1a.z, v1a.w, v1b.x, v1b.y, v1b.z, v1b.w};
#pragma unroll
        for (int p = 0; p < 8; ++p) {
            aLo[p] += __builtin_bit_cast(float, w0[p] << 16);
            aHi[p] += __builtin_bit_cast(float, w0[p] & 0xffff0000u);
            aLo[p] += __builtin_bit_cast(float, w1[p] << 16);
            aHi[p] += __builtin_bit_cast(float, w1[p] & 0xffff0000u);
        }
    }
    // remainder: 1 edge, 2 loads in flight
    for (; j < e; j += 8) {
        int s0 = csr[j];
        const ushort16* r0 = hc + ((size_t)s0 << 7);
        uint4 va = *(const uint4*)(r0);
        uint4 vb = *(const uint4*)(r0 + 64);
        uint32 w[8] = {va.x, va.y, va.z, va.w, vb.x, vb.y, vb.z, vb.w};
#pragma unroll
        for (int p = 0; p < 8; ++p) {
            aLo[p] += __builtin_bit_cast(float, w[p] << 16);
            aHi[p] += __builtin_bit_cast(float, w[p] & 0xffff0000u);
        }
    }
    // reduce across the 8 edge slots (lanes eo*8 + c)
#pragma unroll
    for (int m = 8; m < 64; m <<= 1) {
#pragma unroll
        for (int p = 0; p < 8; ++p) {
            aLo[p] += __shfl_xor(aLo[p], m, 64);
            aHi[p] += __shfl_xor(aHi[p], m, 64);
        }
    }
    if (lane < 8) {
        float inv = 1.f / degf[node];
        uint4 o1, o2;
        o1.x = (uint32)f2bf(aLo[0] * inv) | ((uint32)f2bf(aHi[0] * inv) << 16);
        o1.y = (uint32)f2bf(aLo[1] * inv) | ((uint32)f2bf(aHi[1] * inv) << 16);
        o1.z = (uint32)f2bf(aLo[2] * inv) | ((uint32)f2bf(aHi[2] * inv) << 16);
        o1.w = (uint32)f2bf(aLo[3] * inv) | ((uint32)f2bf(aHi[3] * inv) << 16);
        o2.x = (uint32)f2bf(aLo[4] * inv) | ((uint32)f2bf(aHi[4] * inv) << 16);
        o2.y = (uint32)f2bf(aLo[5] * inv) | ((uint32)f2bf(aHi[5] * inv) << 16);
        o2.z = (uint32)f2bf(aLo[6] * inv) | ((uint32)f2bf(aHi[6] * inv) << 16);
        o2.w = (uint32)f2bf(aLo[7] * inv) | ((uint32)f2bf(aHi[7] * inv) << 16);
        ushort16* ob = aggH + ((size_t)node << 7) + (c << 3);
        *(uint4*)(ob) = o1;
        *(uint4*)(ob + 64) = o2;
    }
}

// ---------------- fused MFMA layer (layers 1-3), v4 (FROZEN) ----------------
// out = bf16( relu( h@Ws + aggH@Wn + bias ) ).
// LEDGER — do not touch this kernel's structure again:
//   v5 reg-resident B        -> compiler remat'd weights  (68.8us, VGPR 64)
//   v6 asm-pinned B          -> still remat/spill         (73.0us, VGPR 60)
//   v7 K-outer loop          -> latency-bound             (~57-61us)
//   v8b weights-LDS-resident -> 4 blocks/CU, lost overlap (+8us/launch)
//   v4+T14 reg-prefetch      -> acc SPILLED TO SCRATCH    (90.9us, VGPR 36,
//                               WRITE_SIZE 25->232MB)
// v4's win = 8 co-resident blocks/CU (20KB LDS, low VGPR) overlapping each
// other's barrier drains. Any register-pressure or LDS increase breaks it.
#define RS 40   // LDS row stride in ushorts (80B, 16B-aligned, bank-spread)
__global__ __launch_bounds__(256) void mfma_fused_kernel(
    const ushort16* __restrict__ A, const ushort16* __restrict__ G,
    const ushort16* __restrict__ Whi, const ushort16* __restrict__ Wlo,
    const float* __restrict__ bias,
    ushort16* __restrict__ Out, int N, int M) {
    __shared__ ushort16 Bs[4][64 * RS];
    const int tid = threadIdx.x;
    const int wave = tid >> 6;
    const int lane = tid & 63;
    const int quad = lane >> 4;
    const int m16 = lane & 15;
    // [0]=Ws_hi, [1]=Ws_lo, [2]=Wn_hi, [3]=Wn_lo
    const ushort16* Wg[4] = {Whi, Wlo, Whi + 16384, Wlo + 16384};

    floatx4 acc[4] = {};                    // 4 n-tiles of 16 cols

    const int n0 = blockIdx.y * 64;         // this block's column half
    int rowA = blockIdx.x * 64 + wave * 16 + m16;
    if (rowA >= N) rowA = N - 1;            // clamp: stores guarded below
    const ushort16* Arow = A + (size_t)rowA * 128;
    const ushort16* Grow = G + (size_t)rowA * 128;

    const int sn = tid >> 2, sh = tid & 3;  // staging: row n (64), 16B quarter
    for (int k0 = 0; k0 < 128; k0 += 32) {
#pragma unroll
        for (int mat = 0; mat < 4; ++mat) {
            const ushort16* g = Wg[mat] + (size_t)(n0 + sn) * 128 + k0 + sh * 8;
            *(uint4*)(&Bs[mat][sn * RS + sh * 8]) = *(const uint4*)g;
        }
        short8 af = *(const short8*)(Arow + k0 + quad * 8);
        short8 gf = *(const short8*)(Grow + k0 + quad * 8);
        __syncthreads();
#pragma unroll
        for (int t = 0; t < 4; ++t) {
            int nb = t * 16 + m16;
            short8 bsh = *(const short8*)(&Bs[0][nb * RS + quad * 8]);
            short8 bsl = *(const short8*)(&Bs[1][nb * RS + quad * 8]);
            short8 bnh = *(const short8*)(&Bs[2][nb * RS + quad * 8]);
            short8 bnl = *(const short8*)(&Bs[3][nb * RS + quad * 8]);
            acc[t] = __builtin_amdgcn_mfma_f32_16x16x32_bf16(af, bsh, acc[t], 0, 0, 0);
            acc[t] = __builtin_amdgcn_mfma_f32_16x16x32_bf16(gf, bnh, acc[t], 0, 0, 0);
            acc[t] = __builtin_amdgcn_mfma_f32_16x16x32_bf16(af, bsl, acc[t], 0, 0, 0);
            acc[t] = __builtin_amdgcn_mfma_f32_16x16x32_bf16(gf, bnl, acc[t], 0, 0, 0);
        }
        __syncthreads();
    }

    // D layout: row = quad*4 + reg, col = n0 + t*16 + m16
    int rowBase = blockIdx.x * 64 + wave * 16 + quad * 4;
#pragma unroll
    for (int t = 0; t < 4; ++t) {
        int colt = n0 + t * 16 + m16;
        bool inc = (colt < M);
        float b = inc ? bias[colt] : 0.f;
#pragma unroll
        for (int r = 0; r < 4; ++r) {
            int row = rowBase + r;
            if (row < N) {
                float v = inc ? fmaxf(acc[t][r] + b, 0.f) : 0.f;
                Out[(size_t)row * 128 + colt] = f2bf(v);
            }
        }
    }
}

// ---------------- layer 4: tiny GEMM (M=5) ----------------
__global__ __launch_bounds__(256) void gemm4_kernel(
    const ushort16* __restrict__ A, const float* __restrict__ ws,
    const float* __restrict__ wn, const float* __restrict__ b4,
    float* __restrict__ Cs, float* __restrict__ Cn, int N, int K, int M) {
    __shared__ float Wsh[520], Wnh[520];
    int tid = threadIdx.x;
    for (int i = tid; i < K * M; i += 256) { Wsh[i] = ws[i]; Wnh[i] = wn[i]; }
    __syncthreads();
    int node = blockIdx.x * 256 + tid;
    if (node >= N) return;
    const ushort16* row = A + ((size_t)node << 7);
    float s[5] = {}, n[5] = {};
    for (int c8 = 0; c8 * 8 < K; ++c8) {
        uint4 v = *(const uint4*)(row + c8 * 8);
        uint32 w[4] = {v.x, v.y, v.z, v.w};
#pragma unroll
        for (int j = 0; j < 8; ++j) {
            int k = c8 * 8 + j;
            if (k < K) {
                float a = (j & 1) ? __builtin_bit_cast(float, w[j >> 1] & 0xffff0000u)
                                  : __builtin_bit_cast(float, w[j >> 1] << 16);
#pragma unroll
                for (int m = 0; m < 5; ++m) {
                    s[m] += a * Wsh[k * 5 + m];
                    n[m] += a * Wnh[k * 5 + m];
                }
            }
        }
    }
    size_t o = (size_t)node * 8;
#pragma unroll
    for (int m = 0; m < 5; ++m) {
        Cs[o + m] = s[m] + b4[m];
        Cn[o + m] = n[m];
    }
#pragma unroll
    for (int m = 5; m < 8; ++m) { Cs[o + m] = 0.f; Cn[o + m] = 0.f; }
}

// ---------------- layer-4 fp32 CSR aggregation, 2 nodes/wave ----------------
// R19: half-wave (32 lanes) per node -> EPI=16 matches mean degree; 2 nodes
// per wave. Reduction via shfl_xor masks 2..16 (stays within each half).
__global__ __launch_bounds__(256) void agg4_kernel(
    const float* __restrict__ hs, const float* __restrict__ hn,
    const int* __restrict__ row_ptr, const int* __restrict__ csr,
    const float* __restrict__ degf, float* __restrict__ out, int N) {
    int wid = threadIdx.x >> 6;
    int lane = threadIdx.x & 63;
    int half = lane >> 5;            // node index within the wave
    int l32 = lane & 31;
    int node = blockIdx.x * 8 + wid * 2 + half;
    if (node >= N) return;
    int s = row_ptr[node], e = row_ptr[node + 1];
    int c = l32 & 1;                 // which 16B half of the 32B row
    int eo = l32 >> 1;               // edge slot 0..15
    float4 acc = make_float4(0.f, 0.f, 0.f, 0.f);
    for (int j = s + eo; j < e; j += 16) {
        int src_n = csr[j];
        float4 v = *(const float4*)(hn + ((size_t)src_n << 3) + (c << 2));
        acc.x += v.x; acc.y += v.y; acc.z += v.z; acc.w += v.w;
    }
#pragma unroll
    for (int m = 2; m < 32; m <<= 1) {
        acc.x += __shfl_xor(acc.x, m, 64);
        acc.y += __shfl_xor(acc.y, m, 64);
        acc.z += __shfl_xor(acc.z, m, 64);
        acc.w += __shfl_xor(acc.w, m, 64);
    }
    if (eo == 0) {
        float d = 1.f / degf[node];
        size_t o = ((size_t)node << 3) + (c << 2);
        float4 hv = *(const float4*)(hs + o);
        float4 r;
        r.x = hv.x + acc.x * d;
        r.y = hv.y + acc.y * d;
        r.z = hv.z + acc.z * d;
        r.w = hv.w + acc.w * d;
        *(float4*)(out + o) = r;
    }
}

// ---------------- per-graph mean pool (stride 8) ----------------
__global__ __launch_bounds__(256) void pool_kernel(
    const float* __restrict__ h, float* __restrict__ out, int npg) {
    __shared__ float sh[4][5];
    int g = blockIdx.x;
    int t = threadIdx.x;
    float acc[5] = {0.f, 0.f, 0.f, 0.f, 0.f};
    int base = g * npg;
    for (int i = t; i < npg; i += 256) {
        const float* r = h + ((size_t)(base + i) << 3);
#pragma unroll
        for (int f = 0; f < 5; ++f) acc[f] += r[f];
    }
#pragma unroll
    for (int off = 32; off > 0; off >>= 1) {
#pragma unroll
        for (int f = 0; f < 5; ++f) acc[f] += __shfl_down(acc[f], off, 64);
    }
    int wid = t >> 6, lane = t & 63;
    if (lane == 0) {
#pragma unroll
        for (int f = 0; f < 5; ++f) sh[wid][f] = acc[f];
    }
    __syncthreads();
    if (t == 0) {
        float inv = 1.f / (float)npg;
#pragma unroll
        for (int f = 0; f < 5; ++f)
            out[g * 5 + f] = (sh[0][f] + sh[1][f] + sh[2][f] + sh[3][f]) * inv;
    }
}

extern "C" void kernel_launch(void* const* d_in, const int* in_sizes, int n_in,
                              void* d_out, int out_size, void* d_ws, size_t ws_size,
                              hipStream_t stream) {
    const float* in_feat = (const float*)d_in[0];
    const int* src = (const int*)d_in[1];
    const int* dst = (const int*)d_in[2];
    const int DIMS[5] = {128, 128, 118, 103, 5};
    const int N = in_sizes[0] / 128;
    const int E = in_sizes[1];
    const int G = out_size / 5;
    const int NBUCK = (N + 255) >> 8;   // 256-node dst buckets (<=512 for LDS)

    char* base = (char*)d_ws;
    size_t off = 0;
    auto carve = [&](size_t bytes) -> void* {
        off = (off + 255) & ~(size_t)255;
        void* p = base + off;
        off += bytes;
        return p;
    };
    int* bcnt = (int*)carve((size_t)NBUCK * 4);
    int* bucketOff = (int*)carve((size_t)(NBUCK + 1) * 4);
    int* cursorA = (int*)carve((size_t)NBUCK * 4);
    int* row_ptr = (int*)carve((size_t)(N + 1) * 4);
    float* degf = (float*)carve((size_t)N * 4);
    uint32* ebuf = (uint32*)carve((size_t)E * 4);
    int* csr = (int*)carve((size_t)E * 4);
    ushort16* buf0 = (ushort16*)carve((size_t)(N + 256) * 128 * 2);
    ushort16* buf1 = (ushort16*)carve((size_t)(N + 256) * 128 * 2);
    ushort16* aggH = (ushort16*)carve((size_t)(N + 256) * 128 * 2);
    ushort16* Whi = (ushort16*)carve((size_t)6 * 16384 * 2);
    ushort16* Wlo = (ushort16*)carve((size_t)6 * 16384 * 2);
    float* Cs4 = (float*)carve((size_t)N * 8 * 4);
    float* Cn4 = (float*)carve((size_t)N * 8 * 4);
    float* out4 = (float*)carve((size_t)N * 8 * 4);
    (void)n_in; (void)ws_size;

    // fused prep: hist + bf16 conv + weight prep (one launch)
    int n8 = N * 16;   // N*128/8
    int HB = (E + PBS - 1) / PBS;
    int CB = (n8 + 255) / 256;
    hipMemsetAsync(bcnt, 0, (size_t)NBUCK * 4, stream);
    prep_fused_kernel<<<HB + CB + 6 * 64, 256, 0, stream>>>(
        dst, bcnt, E, NBUCK, HB,
        in_feat, buf0, n8, CB,
        (const float*)d_in[4], (const float*)d_in[5],
        (const float*)d_in[7], (const float*)d_in[8],
        (const float*)d_in[10], (const float*)d_in[11],
        Whi, Wlo);
    bucket_scan_kernel<<<1, 256, 0, stream>>>(bcnt, bucketOff, cursorA, NBUCK, E);
    bucket_partition_kernel<<<(E + PBS - 1) / PBS, 256, 0, stream>>>(
        src, dst, cursorA, ebuf, E, NBUCK);
    bucket_build_kernel<<<NBUCK, 256, 0, stream>>>(
        ebuf, bucketOff, row_ptr, degf, csr, N, E);

    // layers 1-3: aggregate-first, then fused MFMA (v4: 64x64 tiles, grid x2 cols)
    ushort16* hb[4] = {buf0, buf1, buf0, buf1};
    dim3 ggrid((N + 63) / 64, 2);
    for (int l = 0; l < 3; ++l) {
        int M = DIMS[l + 1];
        const float* b = (const float*)d_in[6 + 3 * l];
        aggregate_pre_kernel<0><<<(N + 3) / 4, 256, 0, stream>>>(
            hb[l], row_ptr, csr, degf, aggH, N);
        mfma_fused_kernel<<<ggrid, 256, 0, stream>>>(
            hb[l], aggH, Whi + (size_t)l * 2 * 16384, Wlo + (size_t)l * 2 * 16384,
            b, hb[l + 1], N, M);
    }

    // layer 4 (aggregate-after: dout=5) + pool
    gemm4_kernel<<<(N + 255) / 256, 256, 0, stream>>>(
        hb[3], (const float*)d_in[13], (const float*)d_in[14], (const float*)d_in[15],
        Cs4, Cn4, N, DIMS[3], DIMS[4]);
    agg4_kernel<<<(N + 7) / 8, 256, 0, stream>>>(
        Cs4, Cn4, row_ptr, csr, degf, out4, N);
    pool_kernel<<<G, 256, 0, stream>>>(out4, (float*)d_out, N / G);
}

// Round 13
// 499.148 us; speedup vs baseline: 1.0277x; 1.0277x over previous
//
#include <hip/hip_runtime.h>
#include <cstdint>
#include <cstddef>

typedef unsigned int uint32;
typedef unsigned short ushort16;   // scalar ushort (bf16 storage)
typedef __attribute__((ext_vector_type(8))) short short8;
typedef __attribute__((ext_vector_type(4))) float floatx4;

__device__ __forceinline__ ushort16 f2bf(float f) {
    uint32 u = __builtin_bit_cast(uint32, f);
    uint32 r = (u + 0x7fffu + ((u >> 16) & 1u)) >> 16;   // RNE
    return (ushort16)r;
}
__device__ __forceinline__ float bf2f(ushort16 h) {
    uint32 u = ((uint32)h) << 16;
    return __builtin_bit_cast(float, u);
}

#define PBS 4096

// ---------------- graph prep: bucketed CSR build ----------------
// bucket_hist is fused into prep_fused_kernel (launch-count cut, R17).
__global__ __launch_bounds__(256) void bucket_scan_kernel(
    const int* __restrict__ bcnt, int* __restrict__ bucketOff,
    int* __restrict__ cursorA, int NBUCK, int E) {
    __shared__ int a[512], b[512];
    int t = threadIdx.x;
    a[t] = (t < NBUCK) ? bcnt[t] : 0;
    a[t + 256] = (t + 256 < NBUCK) ? bcnt[t + 256] : 0;
    __syncthreads();
    int* cur = a; int* nxt = b;
    for (int o = 1; o < 512; o <<= 1) {
#pragma unroll
        for (int i = t; i < 512; i += 256)
            nxt[i] = cur[i] + ((i >= o) ? cur[i - o] : 0);
        __syncthreads();
        int* tmp = cur; cur = nxt; nxt = tmp;
    }
#pragma unroll
    for (int i = t; i < 512; i += 256) {
        if (i < NBUCK) {
            int off = (i == 0) ? 0 : cur[i - 1];
            bucketOff[i] = off;
            cursorA[i] = off;
        }
    }
    if (t == 0) bucketOff[NBUCK] = E;
}

__global__ __launch_bounds__(256) void bucket_partition_kernel(
    const int* __restrict__ src, const int* __restrict__ dst,
    int* __restrict__ cursorA, uint32* __restrict__ ebuf, int E, int NBUCK) {
    __shared__ int lbase[512];
    int tid = threadIdx.x;
    for (int b = tid; b < NBUCK; b += 256) lbase[b] = 0;
    __syncthreads();
    int e0 = blockIdx.x * PBS;
    int e1 = e0 + PBS; if (e1 > E) e1 = E;
    for (int j = e0 + tid; j < e1; j += 256)
        atomicAdd(&lbase[dst[j] >> 8], 1);
    __syncthreads();
    for (int b = tid; b < NBUCK; b += 256) {
        int c = lbase[b];
        lbase[b] = c ? atomicAdd(&cursorA[b], c) : 0;
    }
    __syncthreads();
    for (int j = e0 + tid; j < e1; j += 256) {
        int d = dst[j];
        int p = atomicAdd(&lbase[d >> 8], 1);
        ebuf[p] = ((uint32)src[j] << 8) | (uint32)(d & 255);
    }
}

// R21: replaced the 256-wide Hillis-Steele scan (16 __syncthreads) with a
// wave-level __shfl_up inclusive scan + 4-wave LDS combine (~4 barriers).
// Integer-exact; isolated kernel.
__global__ __launch_bounds__(256) void bucket_build_kernel(
    const uint32* __restrict__ ebuf, const int* __restrict__ bucketOff,
    int* __restrict__ row_ptr, float* __restrict__ degf,
    int* __restrict__ csr, int N, int E) {
    __shared__ int ldeg[256];
    __shared__ int lcur[256];
    __shared__ int wsum[4];
    int b = blockIdx.x, t = threadIdx.x;
    int lane = t & 63, wid = t >> 6;
    int n0 = b << 8;
    int s = bucketOff[b], e = bucketOff[b + 1];
    ldeg[t] = 0;
    __syncthreads();
    for (int j = s + t; j < e; j += 256)
        atomicAdd(&ldeg[ebuf[j] & 255u], 1);
    __syncthreads();
    int v = ldeg[t];
    // intra-wave inclusive scan (6 shfl_up steps, no barriers)
    int x = v;
#pragma unroll
    for (int m = 1; m < 64; m <<= 1) {
        int y = __shfl_up(x, m, 64);
        if (lane >= m) x += y;
    }
    if (lane == 63) wsum[wid] = x;
    __syncthreads();
    int base = 0;
#pragma unroll
    for (int w = 0; w < 4; ++w)
        base += (w < wid) ? wsum[w] : 0;
    int excl = base + x - v;
    int node = n0 + t;
    if (node < N) {
        row_ptr[node] = s + excl;
        degf[node] = (float)(v > 0 ? v : 1);
    }
    lcur[t] = s + excl;
    __syncthreads();
    for (int j = s + t; j < e; j += 256) {
        uint32 en = ebuf[j];
        int p = atomicAdd(&lcur[en & 255u], 1);
        csr[p] = (int)(en >> 8);
    }
    if (b == 0 && t == 0) row_ptr[N] = E;
}

// ---------------- fused prep: bucket hist + bf16 conv + weight prep ----------
// Block ranges:
//   [0, HB)                : dst bucket histogram (needs bcnt pre-zeroed)
//   [HB, HB+CB)            : in_feat fp32 -> bf16 pack
//   [HB+CB, HB+CB+384)     : weight transpose/pad, bf16 hi+lo
__global__ __launch_bounds__(256) void prep_fused_kernel(
    const int* __restrict__ dst, int* __restrict__ bcnt, int E, int NBUCK, int HB,
    const float* __restrict__ x, ushort16* __restrict__ y, int n8, int CB,
    const float* __restrict__ W0s, const float* __restrict__ W0n,
    const float* __restrict__ W1s, const float* __restrict__ W1n,
    const float* __restrict__ W2s, const float* __restrict__ W2n,
    ushort16* __restrict__ Whi, ushort16* __restrict__ Wlo) {
    __shared__ int l[512];
    int t = threadIdx.x;
    int bid = blockIdx.x;
    if (bid < HB) {
        for (int b = t; b < NBUCK; b += 256) l[b] = 0;
        __syncthreads();
        int e0 = bid * PBS;
        int e1 = e0 + PBS; if (e1 > E) e1 = E;
        for (int j = e0 + t; j < e1; j += 256)
            atomicAdd(&l[dst[j] >> 8], 1);
        __syncthreads();
        for (int b = t; b < NBUCK; b += 256) {
            int c = l[b];
            if (c) atomicAdd(&bcnt[b], c);
        }
        return;
    }
    bid -= HB;
    if (bid < CB) {
        int i = bid * 256 + t;
        if (i >= n8) return;
        const float4 a = *(const float4*)(x + (size_t)i * 8);
        const float4 b = *(const float4*)(x + (size_t)i * 8 + 4);
        uint4 o;
        o.x = (uint32)f2bf(a.x) | ((uint32)f2bf(a.y) << 16);
        o.y = (uint32)f2bf(a.z) | ((uint32)f2bf(a.w) << 16);
        o.z = (uint32)f2bf(b.x) | ((uint32)f2bf(b.y) << 16);
        o.w = (uint32)f2bf(b.z) | ((uint32)f2bf(b.w) << 16);
        *(uint4*)(y + (size_t)i * 8) = o;
        return;
    }
    bid -= CB;
    {
        int mat = bid >> 6;
        int idx = (bid & 63) * 256 + t;
        const float* Wt[6] = {W0s, W0n, W1s, W1n, W2s, W2n};
        const int Kt[6] = {128, 128, 128, 128, 118, 118};
        const int Mt[6] = {128, 128, 118, 118, 103, 103};
        int n = idx >> 7, k = idx & 127;
        int K = Kt[mat], M = Mt[mat];
        float w = (k < K && n < M) ? Wt[mat][(size_t)k * M + n] : 0.f;
        ushort16 h = f2bf(w);
        float lo = w - bf2f(h);
        Whi[(size_t)mat * 16384 + idx] = h;
        Wlo[(size_t)mat * 16384 + idx] = f2bf(lo);
    }
}

// ---------------- bf16 CSR pre-aggregation (layers 1-3) ----------------
// FROZEN at measured best (59.8us): 16 lanes/row, aLo/aHi scalar accums,
// UNROLL-4 main + UNROLL-2 mid + remainder.
// LEDGER: pk_add float2 (+0.5us ✗), 8-lane/32B rows (+3us, VALU 50->62 ✗).
template<int UNROLL>
__global__ __launch_bounds__(256) void aggregate_pre_kernel(
    const ushort16* __restrict__ h,
    const int* __restrict__ row_ptr, const int* __restrict__ csr,
    const float* __restrict__ degf, ushort16* __restrict__ aggH, int N) {
    int wid = threadIdx.x >> 6;
    int lane = threadIdx.x & 63;
    int node = blockIdx.x * 4 + wid;
    if (node >= N) return;
    int s = row_ptr[node], e = row_ptr[node + 1];
    int c = lane & 15;
    int eo = lane >> 4;
    float aLo[4] = {}, aHi[4] = {};
    int j = s + eo;
    for (; j + (UNROLL - 1) * 4 < e; j += UNROLL * 4) {
        uint4 v[UNROLL];
#pragma unroll
        for (int u = 0; u < UNROLL; ++u) {
            int src_n = csr[j + u * 4];
            v[u] = *(const uint4*)(h + ((size_t)src_n << 7) + (c << 3));
        }
#pragma unroll
        for (int u = 0; u < UNROLL; ++u) {
            uint32 w[4] = {v[u].x, v[u].y, v[u].z, v[u].w};
#pragma unroll
            for (int p = 0; p < 4; ++p) {
                aLo[p] += __builtin_bit_cast(float, w[p] << 16);
                aHi[p] += __builtin_bit_cast(float, w[p] & 0xffff0000u);
            }
        }
    }
    // mid-loop: 2 edges per lane-group in flight
    for (; j + 4 < e; j += 8) {
        int s0 = csr[j];
        int s1 = csr[j + 4];
        uint4 v0 = *(const uint4*)(h + ((size_t)s0 << 7) + (c << 3));
        uint4 v1 = *(const uint4*)(h + ((size_t)s1 << 7) + (c << 3));
        uint32 w0[4] = {v0.x, v0.y, v0.z, v0.w};
        uint32 w1[4] = {v1.x, v1.y, v1.z, v1.w};
#pragma unroll
        for (int p = 0; p < 4; ++p) {
            aLo[p] += __builtin_bit_cast(float, w0[p] << 16);
            aHi[p] += __builtin_bit_cast(float, w0[p] & 0xffff0000u);
            aLo[p] += __builtin_bit_cast(float, w1[p] << 16);
            aHi[p] += __builtin_bit_cast(float, w1[p] & 0xffff0000u);
        }
    }
    for (; j < e; j += 4) {
        int src_n = csr[j];
        uint4 v = *(const uint4*)(h + ((size_t)src_n << 7) + (c << 3));
        uint32 w[4] = {v.x, v.y, v.z, v.w};
#pragma unroll
        for (int p = 0; p < 4; ++p) {
            aLo[p] += __builtin_bit_cast(float, w[p] << 16);
            aHi[p] += __builtin_bit_cast(float, w[p] & 0xffff0000u);
        }
    }
#pragma unroll
    for (int m = 16; m < 64; m <<= 1) {
#pragma unroll
        for (int p = 0; p < 4; ++p) {
            aLo[p] += __shfl_xor(aLo[p], m, 64);
            aHi[p] += __shfl_xor(aHi[p], m, 64);
        }
    }
    if (lane < 16) {
        float inv = 1.f / degf[node];
        uint4 ov;
        ov.x = (uint32)f2bf(aLo[0] * inv) | ((uint32)f2bf(aHi[0] * inv) << 16);
        ov.y = (uint32)f2bf(aLo[1] * inv) | ((uint32)f2bf(aHi[1] * inv) << 16);
        ov.z = (uint32)f2bf(aLo[2] * inv) | ((uint32)f2bf(aHi[2] * inv) << 16);
        ov.w = (uint32)f2bf(aLo[3] * inv) | ((uint32)f2bf(aHi[3] * inv) << 16);
        *(uint4*)(aggH + ((size_t)node << 7) + (c << 3)) = ov;
    }
}

// ---------------- fused MFMA layer (layers 1-3), v4 (FROZEN) ----------------
// out = bf16( relu( h@Ws + aggH@Wn + bias ) ).
// LEDGER — do not touch this kernel's structure again:
//   v5 reg-resident B        -> compiler remat'd weights  (68.8us, VGPR 64)
//   v6 asm-pinned B          -> still remat/spill         (73.0us, VGPR 60)
//   v7 K-outer loop          -> latency-bound             (~57-61us)
//   v8b weights-LDS-resident -> 4 blocks/CU, lost overlap (+8us/launch)
//   v4+T14 reg-prefetch      -> acc SPILLED TO SCRATCH    (90.9us, VGPR 36,
//                               WRITE_SIZE 25->232MB)
// v4's win = 8 co-resident blocks/CU (20KB LDS, low VGPR) overlapping each
// other's barrier drains. Any register-pressure or LDS increase breaks it.
#define RS 40   // LDS row stride in ushorts (80B, 16B-aligned, bank-spread)
__global__ __launch_bounds__(256) void mfma_fused_kernel(
    const ushort16* __restrict__ A, const ushort16* __restrict__ G,
    const ushort16* __restrict__ Whi, const ushort16* __restrict__ Wlo,
    const float* __restrict__ bias,
    ushort16* __restrict__ Out, int N, int M) {
    __shared__ ushort16 Bs[4][64 * RS];
    const int tid = threadIdx.x;
    const int wave = tid >> 6;
    const int lane = tid & 63;
    const int quad = lane >> 4;
    const int m16 = lane & 15;
    // [0]=Ws_hi, [1]=Ws_lo, [2]=Wn_hi, [3]=Wn_lo
    const ushort16* Wg[4] = {Whi, Wlo, Whi + 16384, Wlo + 16384};

    floatx4 acc[4] = {};                    // 4 n-tiles of 16 cols

    const int n0 = blockIdx.y * 64;         // this block's column half
    int rowA = blockIdx.x * 64 + wave * 16 + m16;
    if (rowA >= N) rowA = N - 1;            // clamp: stores guarded below
    const ushort16* Arow = A + (size_t)rowA * 128;
    const ushort16* Grow = G + (size_t)rowA * 128;

    const int sn = tid >> 2, sh = tid & 3;  // staging: row n (64), 16B quarter
    for (int k0 = 0; k0 < 128; k0 += 32) {
#pragma unroll
        for (int mat = 0; mat < 4; ++mat) {
            const ushort16* g = Wg[mat] + (size_t)(n0 + sn) * 128 + k0 + sh * 8;
            *(uint4*)(&Bs[mat][sn * RS + sh * 8]) = *(const uint4*)g;
        }
        short8 af = *(const short8*)(Arow + k0 + quad * 8);
        short8 gf = *(const short8*)(Grow + k0 + quad * 8);
        __syncthreads();
#pragma unroll
        for (int t = 0; t < 4; ++t) {
            int nb = t * 16 + m16;
            short8 bsh = *(const short8*)(&Bs[0][nb * RS + quad * 8]);
            short8 bsl = *(const short8*)(&Bs[1][nb * RS + quad * 8]);
            short8 bnh = *(const short8*)(&Bs[2][nb * RS + quad * 8]);
            short8 bnl = *(const short8*)(&Bs[3][nb * RS + quad * 8]);
            acc[t] = __builtin_amdgcn_mfma_f32_16x16x32_bf16(af, bsh, acc[t], 0, 0, 0);
            acc[t] = __builtin_amdgcn_mfma_f32_16x16x32_bf16(gf, bnh, acc[t], 0, 0, 0);
            acc[t] = __builtin_amdgcn_mfma_f32_16x16x32_bf16(af, bsl, acc[t], 0, 0, 0);
            acc[t] = __builtin_amdgcn_mfma_f32_16x16x32_bf16(gf, bnl, acc[t], 0, 0, 0);
        }
        __syncthreads();
    }

    // D layout: row = quad*4 + reg, col = n0 + t*16 + m16
    int rowBase = blockIdx.x * 64 + wave * 16 + quad * 4;
#pragma unroll
    for (int t = 0; t < 4; ++t) {
        int colt = n0 + t * 16 + m16;
        bool inc = (colt < M);
        float b = inc ? bias[colt] : 0.f;
#pragma unroll
        for (int r = 0; r < 4; ++r) {
            int row = rowBase + r;
            if (row < N) {
                float v = inc ? fmaxf(acc[t][r] + b, 0.f) : 0.f;
                Out[(size_t)row * 128 + colt] = f2bf(v);
            }
        }
    }
}

// ---------------- layer 4: tiny GEMM (M=5) ----------------
__global__ __launch_bounds__(256) void gemm4_kernel(
    const ushort16* __restrict__ A, const float* __restrict__ ws,
    const float* __restrict__ wn, const float* __restrict__ b4,
    float* __restrict__ Cs, float* __restrict__ Cn, int N, int K, int M) {
    __shared__ float Wsh[520], Wnh[520];
    int tid = threadIdx.x;
    for (int i = tid; i < K * M; i += 256) { Wsh[i] = ws[i]; Wnh[i] = wn[i]; }
    __syncthreads();
    int node = blockIdx.x * 256 + tid;
    if (node >= N) return;
    const ushort16* row = A + ((size_t)node << 7);
    float s[5] = {}, n[5] = {};
    for (int c8 = 0; c8 * 8 < K; ++c8) {
        uint4 v = *(const uint4*)(row + c8 * 8);
        uint32 w[4] = {v.x, v.y, v.z, v.w};
#pragma unroll
        for (int j = 0; j < 8; ++j) {
            int k = c8 * 8 + j;
            if (k < K) {
                float a = (j & 1) ? __builtin_bit_cast(float, w[j >> 1] & 0xffff0000u)
                                  : __builtin_bit_cast(float, w[j >> 1] << 16);
#pragma unroll
                for (int m = 0; m < 5; ++m) {
                    s[m] += a * Wsh[k * 5 + m];
                    n[m] += a * Wnh[k * 5 + m];
                }
            }
        }
    }
    size_t o = (size_t)node * 8;
#pragma unroll
    for (int m = 0; m < 5; ++m) {
        Cs[o + m] = s[m] + b4[m];
        Cn[o + m] = n[m];
    }
#pragma unroll
    for (int m = 5; m < 8; ++m) { Cs[o + m] = 0.f; Cn[o + m] = 0.f; }
}

// ---------------- layer-4 fp32 CSR aggregation, 2 nodes/wave ----------------
// R19: half-wave (32 lanes) per node -> EPI=16 matches mean degree; 2 nodes
// per wave. Reduction via shfl_xor masks 2..16 (stays within each half).
__global__ __launch_bounds__(256) void agg4_kernel(
    const float* __restrict__ hs, const float* __restrict__ hn,
    const int* __restrict__ row_ptr, const int* __restrict__ csr,
    const float* __restrict__ degf, float* __restrict__ out, int N) {
    int wid = threadIdx.x >> 6;
    int lane = threadIdx.x & 63;
    int half = lane >> 5;            // node index within the wave
    int l32 = lane & 31;
    int node = blockIdx.x * 8 + wid * 2 + half;
    if (node >= N) return;
    int s = row_ptr[node], e = row_ptr[node + 1];
    int c = l32 & 1;                 // which 16B half of the 32B row
    int eo = l32 >> 1;               // edge slot 0..15
    float4 acc = make_float4(0.f, 0.f, 0.f, 0.f);
    for (int j = s + eo; j < e; j += 16) {
        int src_n = csr[j];
        float4 v = *(const float4*)(hn + ((size_t)src_n << 3) + (c << 2));
        acc.x += v.x; acc.y += v.y; acc.z += v.z; acc.w += v.w;
    }
#pragma unroll
    for (int m = 2; m < 32; m <<= 1) {
        acc.x += __shfl_xor(acc.x, m, 64);
        acc.y += __shfl_xor(acc.y, m, 64);
        acc.z += __shfl_xor(acc.z, m, 64);
        acc.w += __shfl_xor(acc.w, m, 64);
    }
    if (eo == 0) {
        float d = 1.f / degf[node];
        size_t o = ((size_t)node << 3) + (c << 2);
        float4 hv = *(const float4*)(hs + o);
        float4 r;
        r.x = hv.x + acc.x * d;
        r.y = hv.y + acc.y * d;
        r.z = hv.z + acc.z * d;
        r.w = hv.w + acc.w * d;
        *(float4*)(out + o) = r;
    }
}

// ---------------- per-graph mean pool (stride 8) ----------------
__global__ __launch_bounds__(256) void pool_kernel(
    const float* __restrict__ h, float* __restrict__ out, int npg) {
    __shared__ float sh[4][5];
    int g = blockIdx.x;
    int t = threadIdx.x;
    float acc[5] = {0.f, 0.f, 0.f, 0.f, 0.f};
    int base = g * npg;
    for (int i = t; i < npg; i += 256) {
        const float* r = h + ((size_t)(base + i) << 3);
#pragma unroll
        for (int f = 0; f < 5; ++f) acc[f] += r[f];
    }
#pragma unroll
    for (int off = 32; off > 0; off >>= 1) {
#pragma unroll
        for (int f = 0; f < 5; ++f) acc[f] += __shfl_down(acc[f], off, 64);
    }
    int wid = t >> 6, lane = t & 63;
    if (lane == 0) {
#pragma unroll
        for (int f = 0; f < 5; ++f) sh[wid][f] = acc[f];
    }
    __syncthreads();
    if (t == 0) {
        float inv = 1.f / (float)npg;
#pragma unroll
        for (int f = 0; f < 5; ++f)
            out[g * 5 + f] = (sh[0][f] + sh[1][f] + sh[2][f] + sh[3][f]) * inv;
    }
}

extern "C" void kernel_launch(void* const* d_in, const int* in_sizes, int n_in,
                              void* d_out, int out_size, void* d_ws, size_t ws_size,
                              hipStream_t stream) {
    const float* in_feat = (const float*)d_in[0];
    const int* src = (const int*)d_in[1];
    const int* dst = (const int*)d_in[2];
    const int DIMS[5] = {128, 128, 118, 103, 5};
    const int N = in_sizes[0] / 128;
    const int E = in_sizes[1];
    const int G = out_size / 5;
    const int NBUCK = (N + 255) >> 8;   // 256-node dst buckets (<=512 for LDS)

    char* base = (char*)d_ws;
    size_t off = 0;
    auto carve = [&](size_t bytes) -> void* {
        off = (off + 255) & ~(size_t)255;
        void* p = base + off;
        off += bytes;
        return p;
    };
    int* bcnt = (int*)carve((size_t)NBUCK * 4);
    int* bucketOff = (int*)carve((size_t)(NBUCK + 1) * 4);
    int* cursorA = (int*)carve((size_t)NBUCK * 4);
    int* row_ptr = (int*)carve((size_t)(N + 1) * 4);
    float* degf = (float*)carve((size_t)N * 4);
    uint32* ebuf = (uint32*)carve((size_t)E * 4);
    int* csr = (int*)carve((size_t)E * 4);
    ushort16* buf0 = (ushort16*)carve((size_t)(N + 256) * 128 * 2);
    ushort16* buf1 = (ushort16*)carve((size_t)(N + 256) * 128 * 2);
    ushort16* aggH = (ushort16*)carve((size_t)(N + 256) * 128 * 2);
    ushort16* Whi = (ushort16*)carve((size_t)6 * 16384 * 2);
    ushort16* Wlo = (ushort16*)carve((size_t)6 * 16384 * 2);
    float* Cs4 = (float*)carve((size_t)N * 8 * 4);
    float* Cn4 = (float*)carve((size_t)N * 8 * 4);
    float* out4 = (float*)carve((size_t)N * 8 * 4);
    (void)n_in; (void)ws_size;

    // fused prep: hist + bf16 conv + weight prep (one launch)
    int n8 = N * 16;   // N*128/8
    int HB = (E + PBS - 1) / PBS;
    int CB = (n8 + 255) / 256;
    hipMemsetAsync(bcnt, 0, (size_t)NBUCK * 4, stream);
    prep_fused_kernel<<<HB + CB + 6 * 64, 256, 0, stream>>>(
        dst, bcnt, E, NBUCK, HB,
        in_feat, buf0, n8, CB,
        (const float*)d_in[4], (const float*)d_in[5],
        (const float*)d_in[7], (const float*)d_in[8],
        (const float*)d_in[10], (const float*)d_in[11],
        Whi, Wlo);
    bucket_scan_kernel<<<1, 256, 0, stream>>>(bcnt, bucketOff, cursorA, NBUCK, E);
    bucket_partition_kernel<<<(E + PBS - 1) / PBS, 256, 0, stream>>>(
        src, dst, cursorA, ebuf, E, NBUCK);
    bucket_build_kernel<<<NBUCK, 256, 0, stream>>>(
        ebuf, bucketOff, row_ptr, degf, csr, N, E);

    // layers 1-3: aggregate-first, then fused MFMA (v4: 64x64 tiles, grid x2 cols)
    ushort16* hb[4] = {buf0, buf1, buf0, buf1};
    dim3 ggrid((N + 63) / 64, 2);
    for (int l = 0; l < 3; ++l) {
        int M = DIMS[l + 1];
        const float* b = (const float*)d_in[6 + 3 * l];
        aggregate_pre_kernel<4><<<(N + 3) / 4, 256, 0, stream>>>(
            hb[l], row_ptr, csr, degf, aggH, N);
        mfma_fused_kernel<<<ggrid, 256, 0, stream>>>(
            hb[l], aggH, Whi + (size_t)l * 2 * 16384, Wlo + (size_t)l * 2 * 16384,
            b, hb[l + 1], N, M);
    }

    // layer 4 (aggregate-after: dout=5) + pool
    gemm4_kernel<<<(N + 255) / 256, 256, 0, stream>>>(
        hb[3], (const float*)d_in[13], (const float*)d_in[14], (const float*)d_in[15],
        Cs4, Cn4, N, DIMS[3], DIMS[4]);
    agg4_kernel<<<(N + 7) / 8, 256, 0, stream>>>(
        Cs4, Cn4, row_ptr, csr, degf, out4, N);
    pool_kernel<<<G, 256, 0, stream>>>(out4, (float*)d_out, N / G);
}